// Round 3
// baseline (70.010 us; speedup 1.0000x reference)
//
#include <hip/hip_runtime.h>

// GlobalAttention: out = softmax_j(scores) @ H
// scores[i,j] = sum_m lrelu(Wh1[i,m]+Wh2[j,m]) * a[m]
// lrelu(t) = 0.6 t + 0.4|t|; row-constant part drops out of softmax:
// scores'[i,j] = s2[j] + sum_m b[m]*|Wh1[i,m]+Wh2[j,m]|,  b[m]=0.4*a[m],
// s2[j] = 0.6 * sum_m a[m]*Wh2[j,m].
// Pad = 65 (65 == 1 mod 32): strided-row LDS reads are conflict-free;
// most tile reads are broadcast (addr depends on ti or tj only).
// This round: occupancy. Every heavy kernel gets >=1024 blocks (4 blocks/CU).

#define PAD 65

// ---------- K1: Wh[n][m] = sum_k H[n][k] * Wre[m][k]  (n<1024, m<512, k<256)
// Wre[m][k] = W[m&255][(m>>8)*256 + k].  32i x 16m tiles -> grid (32,32)=1024.
__global__ __launch_bounds__(256) void k1_gemm_wh(const float* __restrict__ H,
                                                  const float* __restrict__ W,
                                                  float* __restrict__ Wh) {
    __shared__ float As[32][PAD];
    __shared__ float Bs[16][PAD];
    const int bi = blockIdx.x, bj = blockIdx.y;
    const int t = threadIdx.x;
    const int ti = t >> 4, tj = t & 15;
    const int i0 = ti * 2;
    const int half = bj >> 4;                 // m-tile 16 wide; half = (bj*16)/256
    const int arow = t >> 3, acol = (t & 7) * 8;
    const int brow = t >> 4, bcol = (t & 15) * 4;
    float acc[2] = {0.f, 0.f};
    for (int kc = 0; kc < 256; kc += 64) {
        *(float4*)&As[arow][acol] =
            *(const float4*)&H[(bi * 32 + arow) * 256 + kc + acol];
        *(float4*)&As[arow][acol + 4] =
            *(const float4*)&H[(bi * 32 + arow) * 256 + kc + acol + 4];
        const int wrow = (bj * 16 + brow) & 255;
        *(float4*)&Bs[brow][bcol] =
            *(const float4*)&W[wrow * 512 + half * 256 + kc + bcol];
        __syncthreads();
#pragma unroll
        for (int k = 0; k < 64; k += 4) {
            float4 a0 = *(const float4*)&As[i0][k];
            float4 a1 = *(const float4*)&As[i0 + 1][k];
            float4 b = *(const float4*)&Bs[tj][k];
            acc[0] = fmaf(a0.x, b.x, acc[0]);
            acc[0] = fmaf(a0.y, b.y, acc[0]);
            acc[0] = fmaf(a0.z, b.z, acc[0]);
            acc[0] = fmaf(a0.w, b.w, acc[0]);
            acc[1] = fmaf(a1.x, b.x, acc[1]);
            acc[1] = fmaf(a1.y, b.y, acc[1]);
            acc[1] = fmaf(a1.z, b.z, acc[1]);
            acc[1] = fmaf(a1.w, b.w, acc[1]);
        }
        __syncthreads();
    }
    Wh[(bi * 32 + i0) * 512 + bj * 16 + tj] = acc[0];
    Wh[(bi * 32 + i0 + 1) * 512 + bj * 16 + tj] = acc[1];
}

// ---------- K1b: s2[j] = 0.6 * sum_m a[m] * Wh2[j][m]   (one wave per row)
__global__ __launch_bounds__(256) void k1b_s2(const float* __restrict__ Wh,
                                              const float* __restrict__ a,
                                              float* __restrict__ s2) {
    const int t = threadIdx.x;
    const int lane = t & 63, w = t >> 6;
    const int row = blockIdx.x * 4 + w;
    float4 x = *(const float4*)&Wh[row * 512 + 256 + lane * 4];
    float4 av = *(const float4*)&a[lane * 4];
    float d = x.x * av.x + x.y * av.y + x.z * av.z + x.w * av.w;
#pragma unroll
    for (int off = 32; off > 0; off >>= 1) d += __shfl_xor(d, off);
    if (lane == 0) s2[row] = 0.6f * d;
}

// ---------- K2: partial_z[i][j] = sum_{m in quarter z} b[m]*|Wh1[i][m]+Wh2[j][m]|
// grid (16,16,4): z splits m 4 ways -> 4 partial buffers (sc + z*1M floats).
__global__ __launch_bounds__(256) void k2_scores(const float* __restrict__ Wh,
                                                 const float* __restrict__ a,
                                                 float* __restrict__ sc) {
    __shared__ float X1[64][PAD];
    __shared__ float X2[64][PAD];
    __shared__ float bsh[64];
    const int bi = blockIdx.x, bj = blockIdx.y, bz = blockIdx.z;
    const int t = threadIdx.x;
    const int ti = t >> 4, tj = t & 15;
    const int i0 = ti * 4, j0 = tj * 4;
    const int m0 = bz * 64;
    if (t < 16) {
        float4 av = *(const float4*)&a[m0 + t * 4];
        *(float4*)&bsh[t * 4] =
            make_float4(0.4f * av.x, 0.4f * av.y, 0.4f * av.z, 0.4f * av.w);
    }
#pragma unroll
    for (int rr = 0; rr < 4; ++rr) {
        const int row = ti + rr * 16;
        const int col = tj * 4;
        *(float4*)&X1[row][col] =
            *(const float4*)&Wh[(bi * 64 + row) * 512 + m0 + col];
        *(float4*)&X2[row][col] =
            *(const float4*)&Wh[(bj * 64 + row) * 512 + 256 + m0 + col];
    }
    __syncthreads();
    float acc[4][4] = {};
#pragma unroll
    for (int k = 0; k < 64; k += 4) {
        float4 x1[4], x2[4];
#pragma unroll
        for (int r = 0; r < 4; ++r) x1[r] = *(const float4*)&X1[i0 + r][k];
#pragma unroll
        for (int c = 0; c < 4; ++c) x2[c] = *(const float4*)&X2[j0 + c][k];
        const float4 bv = *(const float4*)&bsh[k];
#pragma unroll
        for (int r = 0; r < 4; ++r)
#pragma unroll
            for (int c = 0; c < 4; ++c) {
                acc[r][c] = fmaf(fabsf(x1[r].x + x2[c].x), bv.x, acc[r][c]);
                acc[r][c] = fmaf(fabsf(x1[r].y + x2[c].y), bv.y, acc[r][c]);
                acc[r][c] = fmaf(fabsf(x1[r].z + x2[c].z), bv.z, acc[r][c]);
                acc[r][c] = fmaf(fabsf(x1[r].w + x2[c].w), bv.w, acc[r][c]);
            }
    }
    float* dst = sc + (size_t)bz * (1u << 20);
#pragma unroll
    for (int r = 0; r < 4; ++r) {
        float4 v = make_float4(acc[r][0], acc[r][1], acc[r][2], acc[r][3]);
        *(float4*)&dst[(bi * 64 + i0 + r) * 1024 + bj * 64 + j0] = v;
    }
}

// ---------- K3: row softmax of (p0+p1+p2+p3 + s2[j]) -> alpha into p0
__global__ __launch_bounds__(256) void k3_softmax(float* __restrict__ sc,
                                                  const float* __restrict__ s2) {
    const int i = blockIdx.x, t = threadIdx.x;
    __shared__ float red[8];
    const int base = i * 1024 + t * 4;
    float4 v0 = *(float4*)&sc[base];
    float4 v1 = *(const float4*)&sc[(1u << 20) + base];
    float4 v2 = *(const float4*)&sc[(2u << 20) + base];
    float4 v3 = *(const float4*)&sc[(3u << 20) + base];
    float4 vs = *(const float4*)&s2[t * 4];
    float4 v = make_float4(v0.x + v1.x + v2.x + v3.x + vs.x,
                           v0.y + v1.y + v2.y + v3.y + vs.y,
                           v0.z + v1.z + v2.z + v3.z + vs.z,
                           v0.w + v1.w + v2.w + v3.w + vs.w);
    float m = fmaxf(fmaxf(v.x, v.y), fmaxf(v.z, v.w));
#pragma unroll
    for (int off = 32; off > 0; off >>= 1) m = fmaxf(m, __shfl_xor(m, off));
    const int w = t >> 6;
    if ((t & 63) == 0) red[w] = m;
    __syncthreads();
    const float M = fmaxf(fmaxf(red[0], red[1]), fmaxf(red[2], red[3]));
    float4 e;
    e.x = __expf(v.x - M);
    e.y = __expf(v.y - M);
    e.z = __expf(v.z - M);
    e.w = __expf(v.w - M);
    float s = e.x + e.y + e.z + e.w;
#pragma unroll
    for (int off = 32; off > 0; off >>= 1) s += __shfl_xor(s, off);
    if ((t & 63) == 0) red[4 + w] = s;
    __syncthreads();
    const float rs = 1.0f / (red[4] + red[5] + red[6] + red[7]);
    e.x *= rs; e.y *= rs; e.z *= rs; e.w *= rs;
    *(float4*)&sc[base] = e;
}

// ---------- K4: part[s][i][c] = sum_{j in split s} alpha[i][j]*H[j][c]
// 64i x 32c tiles, j-split 8 -> grid (16, 8, 8) = 1024 blocks.
__global__ __launch_bounds__(256) void k4_av(const float* __restrict__ alpha,
                                             const float* __restrict__ H,
                                             float* __restrict__ part) {
    __shared__ float As[64][PAD];
    __shared__ float Hs[64][33];
    const int bi = blockIdx.x;  // i-tile 0..15
    const int bc = blockIdx.y;  // c-tile 0..7
    const int s = blockIdx.z;   // j-split 0..7
    const int t = threadIdx.x;
    const int ti = t >> 4, tj = t & 15;
    const int i0 = ti * 4, c0 = tj * 2;
    const int hrow = t >> 2, hcol = (t & 3) * 8;
    float acc[4][2] = {};
    for (int jc = s * 128; jc < s * 128 + 128; jc += 64) {
#pragma unroll
        for (int rr = 0; rr < 4; ++rr) {
            const int row = ti + rr * 16;
            const int col = tj * 4;
            *(float4*)&As[row][col] =
                *(const float4*)&alpha[(bi * 64 + row) * 1024 + jc + col];
        }
        *(float4*)&Hs[hrow][hcol] =
            *(const float4*)&H[(jc + hrow) * 256 + bc * 32 + hcol];
        *(float4*)&Hs[hrow][hcol + 4] =
            *(const float4*)&H[(jc + hrow) * 256 + bc * 32 + hcol + 4];
        __syncthreads();
#pragma unroll
        for (int k = 0; k < 64; k += 4) {
            float4 av[4];
            float2 h[4];
#pragma unroll
            for (int r = 0; r < 4; ++r) av[r] = *(const float4*)&As[i0 + r][k];
#pragma unroll
            for (int q = 0; q < 4; ++q) h[q] = *(const float2*)&Hs[k + q][c0];
#pragma unroll
            for (int r = 0; r < 4; ++r) {
                acc[r][0] = fmaf(av[r].x, h[0].x, acc[r][0]);
                acc[r][1] = fmaf(av[r].x, h[0].y, acc[r][1]);
                acc[r][0] = fmaf(av[r].y, h[1].x, acc[r][0]);
                acc[r][1] = fmaf(av[r].y, h[1].y, acc[r][1]);
                acc[r][0] = fmaf(av[r].z, h[2].x, acc[r][0]);
                acc[r][1] = fmaf(av[r].z, h[2].y, acc[r][1]);
                acc[r][0] = fmaf(av[r].w, h[3].x, acc[r][0]);
                acc[r][1] = fmaf(av[r].w, h[3].y, acc[r][1]);
            }
        }
        __syncthreads();
    }
#pragma unroll
    for (int r = 0; r < 4; ++r) {
        float2 v = make_float2(acc[r][0], acc[r][1]);
        *(float2*)&part[s * 262144 + (bi * 64 + i0 + r) * 256 + bc * 32 + c0] = v;
    }
}

// ---------- K5: out = sum of 8 partials
__global__ __launch_bounds__(256) void k5_reduce(const float* __restrict__ part,
                                                 float* __restrict__ out) {
    const int idx = (blockIdx.x * 256 + threadIdx.x) * 4;
    float4 o = *(const float4*)&part[idx];
#pragma unroll
    for (int s = 1; s < 8; ++s) {
        float4 p = *(const float4*)&part[s * 262144 + idx];
        o.x += p.x; o.y += p.y; o.z += p.z; o.w += p.w;
    }
    *(float4*)&out[idx] = o;
}

extern "C" void kernel_launch(void* const* d_in, const int* in_sizes, int n_in,
                              void* d_out, int out_size, void* d_ws, size_t ws_size,
                              hipStream_t stream) {
    const float* H = (const float*)d_in[0];
    const float* W = (const float*)d_in[1];
    const float* a = (const float*)d_in[2];
    float* out = (float*)d_out;
    float* ws = (float*)d_ws;

    float* sc = ws;                      // 4 x 1M floats: score partials; sc -> alpha
    float* avp = ws + (4u << 20);        // 8 x 256K floats: AV partials
    float* Wh = ws + (6u << 20);         // 512K floats
    float* s2 = ws + (6u << 20) + (512u << 10);  // 1K floats

    hipLaunchKernelGGL(k1_gemm_wh, dim3(32, 32), dim3(256), 0, stream, H, W, Wh);
    hipLaunchKernelGGL(k1b_s2, dim3(256), dim3(256), 0, stream, Wh, a, s2);
    hipLaunchKernelGGL(k2_scores, dim3(16, 16, 4), dim3(256), 0, stream, Wh, a, sc);
    hipLaunchKernelGGL(k3_softmax, dim3(1024), dim3(256), 0, stream, sc, s2);
    hipLaunchKernelGGL(k4_av, dim3(16, 8, 8), dim3(256), 0, stream, sc, H, avp);
    hipLaunchKernelGGL(k5_reduce, dim3(256), dim3(256), 0, stream, avp, out);
}